// Round 10
// baseline (493.548 us; speedup 1.0000x reference)
//
#include <hip/hip_runtime.h>
#include <cstddef>

#define F 256
#define H 256
#define NSTRUCT 1000
#define NSPEC 4
#define TM 64      // tile rows / species padding granularity
#define TPAD 264   // LDS row stride in bf16 elems

typedef __attribute__((ext_vector_type(8))) short bf16x8;
typedef __attribute__((ext_vector_type(4))) float f32x4;

__device__ __forceinline__ unsigned short f2bf(float v) {
  unsigned int u = __float_as_uint(v);
  unsigned int r = (u + 0x7FFFu + ((u >> 16) & 1u)) >> 16;  // RNE
  return (unsigned short)r;
}

__device__ __forceinline__ float bf2f(unsigned short v) {
  return __uint_as_float(((unsigned int)v) << 16);
}

__device__ __forceinline__ float tanh_fast(float x) {
  x = fminf(fmaxf(x, -15.f), 15.f);
  float e = __expf(2.f * x);
  return __fdividef(e - 1.f, e + 1.f);
}

// ---------------- prep kernels ----------------

// Pack W1, W2, W2^T, W1^T into bf16 MFMA-fragment order, kk-major:
// Out[m][s][kk][jt][lane][i] = W[k][j]  (k = kk*32+(lane>>4)*8+i, j = jt*16+(lane&15))
__global__ void prep_w(const float* __restrict__ W1, const float* __restrict__ W2,
                       unsigned short* __restrict__ Out) {
  int t = blockIdx.x * 256 + threadIdx.x;
  if (t >= 4 * NSPEC * 8192) return;
  int m = t >> 15;              // 0:W1 1:W2 2:W2^T 3:W1^T
  int u = t & 32767;
  int lane = u & 63, jt = (u >> 6) & 15, kk = (u >> 10) & 7, s = u >> 13;
  int trans = (m >= 2);
  const float* In = (m == 0 || m == 3) ? W1 : W2;
  int j = jt * 16 + (lane & 15);
  int k0 = kk * 32 + (lane >> 4) * 8;
  const float* base = In + (size_t)s * F * H;
  unsigned short o[8];
  #pragma unroll
  for (int i = 0; i < 8; ++i) {
    int k = k0 + i;
    float v = trans ? base[(size_t)j * 256 + k] : base[(size_t)k * 256 + j];
    o[i] = f2bf(v);
  }
  *(ushort4*)(Out + (size_t)t * 8) = make_ushort4(o[0], o[1], o[2], o[3]);
  *(ushort4*)(Out + (size_t)t * 8 + 4) = make_ushort4(o[4], o[5], o[6], o[7]);
}

__global__ void histogram_kernel(const int* __restrict__ z, int* __restrict__ cnt, int N) {
  int i = blockIdx.x * blockDim.x + threadIdx.x;
  int lane = threadIdx.x & 63;
  int zi = (i < N) ? z[i] : -1;
  #pragma unroll
  for (int s = 0; s < NSPEC; ++s) {
    unsigned long long m = __ballot(zi == s);
    if (m != 0ull && lane == __ffsll((unsigned long long)m) - 1)
      atomicAdd(&cnt[s], __popcll(m));
  }
}

// exclusive padded scan + fill pad slots of perm with -1 (replaces 0.8MB memset)
__global__ void scan_kernel(int* __restrict__ cnt, int* __restrict__ poff,
                            int* __restrict__ perm) {
  int acc = 0;
  for (int s = 0; s < NSPEC; ++s) {
    poff[s] = acc;
    int c = cnt[s];
    int padded = ((c + TM - 1) / TM) * TM;
    for (int i = acc + c; i < acc + padded; ++i) perm[i] = -1;
    acc += padded;
    cnt[s] = 0;
  }
  poff[NSPEC] = acc;
}

__global__ void scatter_kernel(const int* __restrict__ z, const int* __restrict__ poff,
                               int* __restrict__ cnt, int* __restrict__ perm, int N) {
  int i = blockIdx.x * blockDim.x + threadIdx.x;
  int lane = threadIdx.x & 63;
  int zi = (i < N) ? z[i] : -1;
  #pragma unroll
  for (int s = 0; s < NSPEC; ++s) {
    unsigned long long m = __ballot(zi == s);
    if (m == 0ull) continue;
    int leader = __ffsll((unsigned long long)m) - 1;
    int base = 0;
    if (lane == leader) base = atomicAdd(&cnt[s], __popcll(m));
    base = __shfl(base, leader, 64);
    if (zi == s) {
      int rank = __popcll(m & ((1ull << lane) - 1ull));
      perm[poff[s] + base + rank] = i;
    }
  }
}

// ---------------- GEMM core (wave w -> col-tiles {2w,2w+1}, all 4 row-frags) ----------------

__device__ __forceinline__ void gemm64(const unsigned short (*src)[TPAD],
                                       const unsigned short* __restrict__ wf,
                                       int w, int lane, f32x4 acc[4][2]) {
  const int l15 = lane & 15, lk = lane >> 4;
  #pragma unroll
  for (int rt = 0; rt < 4; ++rt)
    #pragma unroll
    for (int q = 0; q < 2; ++q) acc[rt][q] = (f32x4){0.f, 0.f, 0.f, 0.f};
  #pragma unroll
  for (int kk = 0; kk < 8; ++kk) {
    const int kcol = kk * 32 + lk * 8;
    bf16x8 a0 = *(const bf16x8*)&src[l15][kcol];
    bf16x8 a1 = *(const bf16x8*)&src[16 + l15][kcol];
    bf16x8 a2 = *(const bf16x8*)&src[32 + l15][kcol];
    bf16x8 a3 = *(const bf16x8*)&src[48 + l15][kcol];
    #pragma unroll
    for (int q = 0; q < 2; ++q) {
      const int jt = w * 2 + q;
      bf16x8 b = *(const bf16x8*)(wf + ((size_t)(kk * 16 + jt) * 64 + lane) * 8);
      acc[0][q] = __builtin_amdgcn_mfma_f32_16x16x32_bf16(a0, b, acc[0][q], 0, 0, 0);
      acc[1][q] = __builtin_amdgcn_mfma_f32_16x16x32_bf16(a1, b, acc[1][q], 0, 0, 0);
      acc[2][q] = __builtin_amdgcn_mfma_f32_16x16x32_bf16(a2, b, acc[2][q], 0, 0, 0);
      acc[3][q] = __builtin_amdgcn_mfma_f32_16x16x32_bf16(a3, b, acc[3][q], 0, 0, 0);
    }
  }
}

// ---------------- fused MFMA MLP fwd+bwd (round-3 structure) ----------------

__global__ __launch_bounds__(512, 4) void mlp_fused(
    const float* __restrict__ X, const int* __restrict__ smap,
    const unsigned short* __restrict__ Wf,
    const float* __restrict__ b1g, const float* __restrict__ b2g,
    const float* __restrict__ W3g, const float* __restrict__ b3g,
    const float* __restrict__ Wskipg, const float* __restrict__ bskipg,
    const int* __restrict__ perm, const int* __restrict__ poff,
    float* __restrict__ energies, unsigned short* __restrict__ nng)
{
  __shared__ __align__(16) unsigned short bufA[TM][TPAD];
  __shared__ __align__(16) unsigned short bufB[TM][TPAD];
  __shared__ float xskp[TM][8];
  __shared__ float e_lds[TM];
  __shared__ int atom_l[TM];

  const int tid = threadIdx.x;
  const int row0 = blockIdx.x * TM;
  if (row0 >= poff[NSPEC]) return;

  int s = 0;
  #pragma unroll
  for (int q = 1; q < NSPEC; ++q)
    if (row0 >= poff[q]) s = q;

  const size_t WMAT = (size_t)NSPEC * 65536;
  const unsigned short* w1f  = Wf + (size_t)s * 65536;
  const unsigned short* w2f  = Wf + WMAT + (size_t)s * 65536;
  const unsigned short* w2tf = Wf + 2 * WMAT + (size_t)s * 65536;
  const unsigned short* w1tf = Wf + 3 * WMAT + (size_t)s * 65536;
  const float* wsk = Wskipg + s * F;

  // ---- phase 0: stage X (fp32->bf16, nontemporal) + skip-dot partials ----
  {
    const int lr = tid >> 3, lc = tid & 7;
    if (tid < TM) { e_lds[tid] = 0.f; atom_l[tid] = perm[row0 + tid]; }
    const int atomR = perm[row0 + lr];
    float xsk = 0.f;
    if (atomR >= 0) {
      const f32x4* xrow = (const f32x4*)(X + (size_t)atomR * F);
      #pragma unroll
      for (int jj = 0; jj < 8; ++jj) {
        const int fi = lc + jj * 8;
        f32x4 v = __builtin_nontemporal_load(xrow + fi);
        float4 wv = ((const float4*)wsk)[fi];
        xsk += v[0] * wv.x + v[1] * wv.y + v[2] * wv.z + v[3] * wv.w;
        *(ushort4*)&bufA[lr][fi * 4] =
            make_ushort4(f2bf(v[0]), f2bf(v[1]), f2bf(v[2]), f2bf(v[3]));
      }
    } else {
      #pragma unroll
      for (int jj = 0; jj < 8; ++jj)
        *(ushort4*)&bufA[lr][(lc + jj * 8) * 4] = make_ushort4(0, 0, 0, 0);
    }
    xskp[lr][lc] = xsk;
  }
  __syncthreads();

  const int w = tid >> 6, lane = tid & 63;
  const int l15 = lane & 15, lk = lane >> 4;
  f32x4 acc[4][2];

  // ---- GEMM1: h1 = tanh(X @ W1 + b1) -> bufB ----
  gemm64(bufA, w1f, w, lane, acc);
  #pragma unroll
  for (int q = 0; q < 2; ++q) {
    const int col = (w * 2 + q) * 16 + l15;
    const float b1v = b1g[s * H + col];
    #pragma unroll
    for (int rt = 0; rt < 4; ++rt) {
      const int rowb = rt * 16 + lk * 4;
      #pragma unroll
      for (int r = 0; r < 4; ++r)
        bufB[rowb + r][col] = f2bf(tanh_fast(acc[rt][q][r] + b1v));
    }
  }
  __syncthreads();

  // ---- GEMM2: h2 = tanh(h1 @ W2 + b2); energy partials; d2 = (1-h2^2)*W3 -> bufA ----
  gemm64(bufB, w2f, w, lane, acc);
  {
    float ep[4][4];
    #pragma unroll
    for (int rt = 0; rt < 4; ++rt)
      #pragma unroll
      for (int r = 0; r < 4; ++r) ep[rt][r] = 0.f;
    #pragma unroll
    for (int q = 0; q < 2; ++q) {
      const int col = (w * 2 + q) * 16 + l15;
      const float b2v = b2g[s * H + col];
      const float w3v = W3g[s * H + col];
      #pragma unroll
      for (int rt = 0; rt < 4; ++rt) {
        const int rowb = rt * 16 + lk * 4;
        #pragma unroll
        for (int r = 0; r < 4; ++r) {
          float h = tanh_fast(acc[rt][q][r] + b2v);
          ep[rt][r] += h * w3v;
          bufA[rowb + r][col] = f2bf((1.f - h * h) * w3v);
        }
      }
    }
    #pragma unroll
    for (int rt = 0; rt < 4; ++rt)
      #pragma unroll
      for (int r = 0; r < 4; ++r) {
        #pragma unroll
        for (int m = 1; m <= 8; m <<= 1)
          ep[rt][r] += __shfl_xor(ep[rt][r], m, 64);
      }
    if (l15 == 0) {
      #pragma unroll
      for (int rt = 0; rt < 4; ++rt)
        #pragma unroll
        for (int r = 0; r < 4; ++r)
          atomicAdd(&e_lds[rt * 16 + lk * 4 + r], ep[rt][r]);
    }
  }
  __syncthreads();

  // ---- energies finalize ----
  if (tid < TM) {
    int atom = atom_l[tid];
    if (atom >= 0) {
      float xs = 0.f;
      #pragma unroll
      for (int q = 0; q < 8; ++q) xs += xskp[tid][q];
      atomicAdd(&energies[smap[atom]], e_lds[tid] + xs + b3g[s] + bskipg[s]);
    }
  }

  // ---- GEMM3: g1 = d2 @ W2^T; d1 = (1-h1^2)*g1 -> bufB (in-place h1 RMW) ----
  gemm64(bufA, w2tf, w, lane, acc);
  #pragma unroll
  for (int q = 0; q < 2; ++q) {
    const int col = (w * 2 + q) * 16 + l15;
    #pragma unroll
    for (int rt = 0; rt < 4; ++rt) {
      const int rowb = rt * 16 + lk * 4;
      #pragma unroll
      for (int r = 0; r < 4; ++r) {
        float h = bf2f(bufB[rowb + r][col]);
        bufB[rowb + r][col] = f2bf((1.f - h * h) * acc[rt][q][r]);
      }
    }
  }
  __syncthreads();

  // ---- GEMM4: dE/dx = d1 @ W1^T + Wskip -> nng (bf16) ----
  gemm64(bufB, w1tf, w, lane, acc);
  #pragma unroll
  for (int q = 0; q < 2; ++q) {
    const int col = (w * 2 + q) * 16 + l15;
    const float wv = wsk[col];
    #pragma unroll
    for (int rt = 0; rt < 4; ++rt) {
      #pragma unroll
      for (int r = 0; r < 4; ++r) {
        int atom2 = atom_l[rt * 16 + lk * 4 + r];
        if (atom2 >= 0)
          nng[(size_t)atom2 * F + col] = f2bf(acc[rt][q][r] + wv);
      }
    }
  }
}

// ---------------- forces: 4 pairs per wave, 16 lanes each, NT ptg stream ----------------

__global__ __launch_bounds__(256) void force_kernel(
    const float* __restrict__ ptg, const int* __restrict__ gmap,
    const unsigned short* __restrict__ g, float* __restrict__ forces, int P)
{
  const int wave = (int)((blockIdx.x * 256 + threadIdx.x) >> 6);
  const int lane = threadIdx.x & 63;
  const int grp = lane >> 4, l = lane & 15;
  const int p = wave * 4 + grp;
  if (p >= P) return;
  const int a = gmap[p];

  // this lane's 16 contiguous features: f = l*16 .. l*16+15
  const unsigned short* grow = g + (size_t)a * F + l * 16;
  bf16x8 ga = *(const bf16x8*)grow;
  bf16x8 gb = *(const bf16x8*)(grow + 8);
  float gv[16];
  #pragma unroll
  for (int i = 0; i < 8; ++i) {
    gv[i]     = bf2f((unsigned short)ga[i]);
    gv[8 + i] = bf2f((unsigned short)gb[i]);
  }

  const float* pr = ptg + (size_t)p * 3 * F + l * 16;
  f32x4 t[3][4];
  #pragma unroll
  for (int c = 0; c < 3; ++c)
    #pragma unroll
    for (int j = 0; j < 4; ++j)
      t[c][j] = __builtin_nontemporal_load((const f32x4*)(pr + c * F) + j);

  float sc[3];
  #pragma unroll
  for (int c = 0; c < 3; ++c) {
    float s = 0.f;
    #pragma unroll
    for (int j = 0; j < 4; ++j)
      s += t[c][j][0] * gv[j * 4] + t[c][j][1] * gv[j * 4 + 1]
         + t[c][j][2] * gv[j * 4 + 2] + t[c][j][3] * gv[j * 4 + 3];
    sc[c] = s;
  }
  #pragma unroll
  for (int off = 1; off <= 8; off <<= 1) {
    sc[0] += __shfl_xor(sc[0], off, 64);
    sc[1] += __shfl_xor(sc[1], off, 64);
    sc[2] += __shfl_xor(sc[2], off, 64);
  }
  float r = (l == 0) ? sc[0] : ((l == 1) ? sc[1] : sc[2]);
  if (l < 3) atomicAdd(&forces[(size_t)a * 3 + l], -r);
}

// ---------------- launch ----------------

extern "C" void kernel_launch(void* const* d_in, const int* in_sizes, int n_in,
                              void* d_out, int out_size, void* d_ws, size_t ws_size,
                              hipStream_t stream) {
  const float* X     = (const float*)d_in[0];
  const int*   z     = (const int*)d_in[1];
  const int*   smap  = (const int*)d_in[2];
  const float* ptg   = (const float*)d_in[3];
  const int*   gmap  = (const int*)d_in[4];
  const float* W1    = (const float*)d_in[5];
  const float* b1    = (const float*)d_in[6];
  const float* W2    = (const float*)d_in[7];
  const float* b2    = (const float*)d_in[8];
  const float* W3    = (const float*)d_in[9];
  const float* b3    = (const float*)d_in[10];
  const float* Wskip = (const float*)d_in[11];
  const float* bskip = (const float*)d_in[12];

  const int N = in_sizes[1];
  const int P = in_sizes[4];

  char* ws = (char*)d_ws;
  int* cnt  = (int*)ws;
  int* poff = (int*)(ws + 16);
  int* perm = (int*)(ws + 64);
  size_t perm_bytes = (size_t)(N + NSPEC * TM) * sizeof(int);
  size_t off = 64 + perm_bytes;
  off = (off + 255) & ~(size_t)255;
  unsigned short* Wf = (unsigned short*)(ws + off);
  const size_t WMAT = (size_t)NSPEC * 65536;
  off += 4 * WMAT * sizeof(unsigned short);
  off = (off + 255) & ~(size_t)255;
  unsigned short* nng = (unsigned short*)(ws + off);  // N * F bf16

  float* energies = (float*)d_out;
  float* forces   = energies + NSTRUCT;

  hipMemsetAsync(d_out, 0, (size_t)out_size * sizeof(float), stream);
  hipMemsetAsync(cnt, 0, 16, stream);

  prep_w<<<(4 * NSPEC * 8192 + 255) / 256, 256, 0, stream>>>(W1, W2, Wf);

  histogram_kernel<<<(N + 255) / 256, 256, 0, stream>>>(z, cnt, N);
  scan_kernel<<<1, 1, 0, stream>>>(cnt, poff, perm);
  scatter_kernel<<<(N + 255) / 256, 256, 0, stream>>>(z, poff, cnt, perm, N);

  int mlpBlocks = (N + NSPEC * TM + TM - 1) / TM;
  mlp_fused<<<mlpBlocks, 512, 0, stream>>>(X, smap, Wf, b1, b2, W3, b3,
                                           Wskip, bskip, perm, poff,
                                           energies, nng);

  int forceBlocks = (P + 15) / 16;
  force_kernel<<<forceBlocks, 256, 0, stream>>>(ptg, gmap, nng, forces, P);
}

// Round 11
// 396.598 us; speedup vs baseline: 1.2445x; 1.2445x over previous
//
#include <hip/hip_runtime.h>
#include <cstddef>

#define F 256
#define H 256
#define NSTRUCT 1000
#define NSPEC 4
#define TM 64      // tile rows / species padding granularity
#define TPAD 264   // LDS row stride in bf16 elems
#define FCHUNK 4   // pairs per wave in force kernel

typedef __attribute__((ext_vector_type(8))) short bf16x8;
typedef __attribute__((ext_vector_type(4))) float f32x4;

__device__ __forceinline__ unsigned short f2bf(float v) {
  unsigned int u = __float_as_uint(v);
  unsigned int r = (u + 0x7FFFu + ((u >> 16) & 1u)) >> 16;  // RNE
  return (unsigned short)r;
}

__device__ __forceinline__ float bf2f(unsigned short v) {
  return __uint_as_float(((unsigned int)v) << 16);
}

__device__ __forceinline__ float tanh_fast(float x) {
  x = fminf(fmaxf(x, -15.f), 15.f);
  float e = __expf(2.f * x);
  return __fdividef(e - 1.f, e + 1.f);
}

// ---------------- prep kernels ----------------

// Pack W1, W2, W2^T, W1^T into bf16 MFMA-fragment order, kk-major:
// Out[m][s][kk][jt][lane][i] = W[k][j]  (k = kk*32+(lane>>4)*8+i, j = jt*16+(lane&15))
__global__ void prep_w(const float* __restrict__ W1, const float* __restrict__ W2,
                       unsigned short* __restrict__ Out) {
  int t = blockIdx.x * 256 + threadIdx.x;
  if (t >= 4 * NSPEC * 8192) return;
  int m = t >> 15;              // 0:W1 1:W2 2:W2^T 3:W1^T
  int u = t & 32767;
  int lane = u & 63, jt = (u >> 6) & 15, kk = (u >> 10) & 7, s = u >> 13;
  int trans = (m >= 2);
  const float* In = (m == 0 || m == 3) ? W1 : W2;
  int j = jt * 16 + (lane & 15);
  int k0 = kk * 32 + (lane >> 4) * 8;
  const float* base = In + (size_t)s * F * H;
  unsigned short o[8];
  #pragma unroll
  for (int i = 0; i < 8; ++i) {
    int k = k0 + i;
    float v = trans ? base[(size_t)j * 256 + k] : base[(size_t)k * 256 + j];
    o[i] = f2bf(v);
  }
  *(ushort4*)(Out + (size_t)t * 8) = make_ushort4(o[0], o[1], o[2], o[3]);
  *(ushort4*)(Out + (size_t)t * 8 + 4) = make_ushort4(o[4], o[5], o[6], o[7]);
}

__global__ void histogram_kernel(const int* __restrict__ z, int* __restrict__ cnt, int N) {
  int i = blockIdx.x * blockDim.x + threadIdx.x;
  int lane = threadIdx.x & 63;
  int zi = (i < N) ? z[i] : -1;
  #pragma unroll
  for (int s = 0; s < NSPEC; ++s) {
    unsigned long long m = __ballot(zi == s);
    if (m != 0ull && lane == __ffsll((unsigned long long)m) - 1)
      atomicAdd(&cnt[s], __popcll(m));
  }
}

// exclusive padded scan + fill pad slots of perm with -1
__global__ void scan_kernel(int* __restrict__ cnt, int* __restrict__ poff,
                            int* __restrict__ perm) {
  int acc = 0;
  for (int s = 0; s < NSPEC; ++s) {
    poff[s] = acc;
    int c = cnt[s];
    int padded = ((c + TM - 1) / TM) * TM;
    for (int i = acc + c; i < acc + padded; ++i) perm[i] = -1;
    acc += padded;
    cnt[s] = 0;
  }
  poff[NSPEC] = acc;
}

__global__ void scatter_kernel(const int* __restrict__ z, const int* __restrict__ poff,
                               int* __restrict__ cnt, int* __restrict__ perm, int N) {
  int i = blockIdx.x * blockDim.x + threadIdx.x;
  int lane = threadIdx.x & 63;
  int zi = (i < N) ? z[i] : -1;
  #pragma unroll
  for (int s = 0; s < NSPEC; ++s) {
    unsigned long long m = __ballot(zi == s);
    if (m == 0ull) continue;
    int leader = __ffsll((unsigned long long)m) - 1;
    int base = 0;
    if (lane == leader) base = atomicAdd(&cnt[s], __popcll(m));
    base = __shfl(base, leader, 64);
    if (zi == s) {
      int rank = __popcll(m & ((1ull << lane) - 1ull));
      perm[poff[s] + base + rank] = i;
    }
  }
}

// ---------------- GEMM core (wave w -> col-tiles {2w,2w+1}, all 4 row-frags) ----------------

__device__ __forceinline__ void gemm64(const unsigned short (*src)[TPAD],
                                       const unsigned short* __restrict__ wf,
                                       int w, int lane, f32x4 acc[4][2]) {
  const int l15 = lane & 15, lk = lane >> 4;
  #pragma unroll
  for (int rt = 0; rt < 4; ++rt)
    #pragma unroll
    for (int q = 0; q < 2; ++q) acc[rt][q] = (f32x4){0.f, 0.f, 0.f, 0.f};
  #pragma unroll
  for (int kk = 0; kk < 8; ++kk) {
    const int kcol = kk * 32 + lk * 8;
    bf16x8 a0 = *(const bf16x8*)&src[l15][kcol];
    bf16x8 a1 = *(const bf16x8*)&src[16 + l15][kcol];
    bf16x8 a2 = *(const bf16x8*)&src[32 + l15][kcol];
    bf16x8 a3 = *(const bf16x8*)&src[48 + l15][kcol];
    #pragma unroll
    for (int q = 0; q < 2; ++q) {
      const int jt = w * 2 + q;
      bf16x8 b = *(const bf16x8*)(wf + ((size_t)(kk * 16 + jt) * 64 + lane) * 8);
      acc[0][q] = __builtin_amdgcn_mfma_f32_16x16x32_bf16(a0, b, acc[0][q], 0, 0, 0);
      acc[1][q] = __builtin_amdgcn_mfma_f32_16x16x32_bf16(a1, b, acc[1][q], 0, 0, 0);
      acc[2][q] = __builtin_amdgcn_mfma_f32_16x16x32_bf16(a2, b, acc[2][q], 0, 0, 0);
      acc[3][q] = __builtin_amdgcn_mfma_f32_16x16x32_bf16(a3, b, acc[3][q], 0, 0, 0);
    }
  }
}

// ---------------- fused MFMA MLP fwd+bwd (round-3/8 structure) ----------------

__global__ __launch_bounds__(512, 4) void mlp_fused(
    const float* __restrict__ X, const int* __restrict__ smap,
    const unsigned short* __restrict__ Wf,
    const float* __restrict__ b1g, const float* __restrict__ b2g,
    const float* __restrict__ W3g, const float* __restrict__ b3g,
    const float* __restrict__ Wskipg, const float* __restrict__ bskipg,
    const int* __restrict__ perm, const int* __restrict__ poff,
    float* __restrict__ energies, unsigned short* __restrict__ nng)
{
  __shared__ __align__(16) unsigned short bufA[TM][TPAD];
  __shared__ __align__(16) unsigned short bufB[TM][TPAD];
  __shared__ float xskp[TM][8];
  __shared__ float e_lds[TM];
  __shared__ int atom_l[TM];

  const int tid = threadIdx.x;
  const int row0 = blockIdx.x * TM;
  if (row0 >= poff[NSPEC]) return;

  int s = 0;
  #pragma unroll
  for (int q = 1; q < NSPEC; ++q)
    if (row0 >= poff[q]) s = q;

  const size_t WMAT = (size_t)NSPEC * 65536;
  const unsigned short* w1f  = Wf + (size_t)s * 65536;
  const unsigned short* w2f  = Wf + WMAT + (size_t)s * 65536;
  const unsigned short* w2tf = Wf + 2 * WMAT + (size_t)s * 65536;
  const unsigned short* w1tf = Wf + 3 * WMAT + (size_t)s * 65536;
  const float* wsk = Wskipg + s * F;

  // ---- phase 0: stage X (fp32->bf16, nontemporal) + skip-dot partials ----
  {
    const int lr = tid >> 3, lc = tid & 7;
    if (tid < TM) { e_lds[tid] = 0.f; atom_l[tid] = perm[row0 + tid]; }
    const int atomR = perm[row0 + lr];
    float xsk = 0.f;
    if (atomR >= 0) {
      const f32x4* xrow = (const f32x4*)(X + (size_t)atomR * F);
      #pragma unroll
      for (int jj = 0; jj < 8; ++jj) {
        const int fi = lc + jj * 8;
        f32x4 v = __builtin_nontemporal_load(xrow + fi);
        float4 wv = ((const float4*)wsk)[fi];
        xsk += v[0] * wv.x + v[1] * wv.y + v[2] * wv.z + v[3] * wv.w;
        *(ushort4*)&bufA[lr][fi * 4] =
            make_ushort4(f2bf(v[0]), f2bf(v[1]), f2bf(v[2]), f2bf(v[3]));
      }
    } else {
      #pragma unroll
      for (int jj = 0; jj < 8; ++jj)
        *(ushort4*)&bufA[lr][(lc + jj * 8) * 4] = make_ushort4(0, 0, 0, 0);
    }
    xskp[lr][lc] = xsk;
  }
  __syncthreads();

  const int w = tid >> 6, lane = tid & 63;
  const int l15 = lane & 15, lk = lane >> 4;
  f32x4 acc[4][2];

  // ---- GEMM1: h1 = tanh(X @ W1 + b1) -> bufB ----
  gemm64(bufA, w1f, w, lane, acc);
  #pragma unroll
  for (int q = 0; q < 2; ++q) {
    const int col = (w * 2 + q) * 16 + l15;
    const float b1v = b1g[s * H + col];
    #pragma unroll
    for (int rt = 0; rt < 4; ++rt) {
      const int rowb = rt * 16 + lk * 4;
      #pragma unroll
      for (int r = 0; r < 4; ++r)
        bufB[rowb + r][col] = f2bf(tanh_fast(acc[rt][q][r] + b1v));
    }
  }
  __syncthreads();

  // ---- GEMM2: h2 = tanh(h1 @ W2 + b2); energy partials; d2 = (1-h2^2)*W3 -> bufA ----
  gemm64(bufB, w2f, w, lane, acc);
  {
    float ep[4][4];
    #pragma unroll
    for (int rt = 0; rt < 4; ++rt)
      #pragma unroll
      for (int r = 0; r < 4; ++r) ep[rt][r] = 0.f;
    #pragma unroll
    for (int q = 0; q < 2; ++q) {
      const int col = (w * 2 + q) * 16 + l15;
      const float b2v = b2g[s * H + col];
      const float w3v = W3g[s * H + col];
      #pragma unroll
      for (int rt = 0; rt < 4; ++rt) {
        const int rowb = rt * 16 + lk * 4;
        #pragma unroll
        for (int r = 0; r < 4; ++r) {
          float h = tanh_fast(acc[rt][q][r] + b2v);
          ep[rt][r] += h * w3v;
          bufA[rowb + r][col] = f2bf((1.f - h * h) * w3v);
        }
      }
    }
    #pragma unroll
    for (int rt = 0; rt < 4; ++rt)
      #pragma unroll
      for (int r = 0; r < 4; ++r) {
        #pragma unroll
        for (int m = 1; m <= 8; m <<= 1)
          ep[rt][r] += __shfl_xor(ep[rt][r], m, 64);
      }
    if (l15 == 0) {
      #pragma unroll
      for (int rt = 0; rt < 4; ++rt)
        #pragma unroll
        for (int r = 0; r < 4; ++r)
          atomicAdd(&e_lds[rt * 16 + lk * 4 + r], ep[rt][r]);
    }
  }
  __syncthreads();

  // ---- energies finalize ----
  if (tid < TM) {
    int atom = atom_l[tid];
    if (atom >= 0) {
      float xs = 0.f;
      #pragma unroll
      for (int q = 0; q < 8; ++q) xs += xskp[tid][q];
      atomicAdd(&energies[smap[atom]], e_lds[tid] + xs + b3g[s] + bskipg[s]);
    }
  }

  // ---- GEMM3: g1 = d2 @ W2^T; d1 = (1-h1^2)*g1 -> bufB (in-place h1 RMW) ----
  gemm64(bufA, w2tf, w, lane, acc);
  #pragma unroll
  for (int q = 0; q < 2; ++q) {
    const int col = (w * 2 + q) * 16 + l15;
    #pragma unroll
    for (int rt = 0; rt < 4; ++rt) {
      const int rowb = rt * 16 + lk * 4;
      #pragma unroll
      for (int r = 0; r < 4; ++r) {
        float h = bf2f(bufB[rowb + r][col]);
        bufB[rowb + r][col] = f2bf((1.f - h * h) * acc[rt][q][r]);
      }
    }
  }
  __syncthreads();

  // ---- GEMM4: dE/dx = d1 @ W1^T + Wskip -> nng (bf16) ----
  gemm64(bufB, w1tf, w, lane, acc);
  #pragma unroll
  for (int q = 0; q < 2; ++q) {
    const int col = (w * 2 + q) * 16 + l15;
    const float wv = wsk[col];
    #pragma unroll
    for (int rt = 0; rt < 4; ++rt) {
      #pragma unroll
      for (int r = 0; r < 4; ++r) {
        int atom2 = atom_l[rt * 16 + lk * 4 + r];
        if (atom2 >= 0)
          nng[(size_t)atom2 * F + col] = f2bf(acc[rt][q][r] + wv);
      }
    }
  }
}

// ---------------- forces: 1 wave per pair, 4 pairs chunked per wave (pipelined) ----------------

__global__ __launch_bounds__(256) void force_kernel(
    const float* __restrict__ ptg, const int* __restrict__ gmap,
    const unsigned short* __restrict__ g, float* __restrict__ forces, int P)
{
  const int wave = (int)((blockIdx.x * 256 + threadIdx.x) >> 6);
  const int lane = threadIdx.x & 63;
  const int p0 = wave * FCHUNK;
  if (p0 >= P) return;

  int a[FCHUNK];
  ushort4 gu[FCHUNK];
  f32x4 t0[FCHUNK], t1[FCHUNK], t2[FCHUNK];

  // issue all index loads
  #pragma unroll
  for (int i = 0; i < FCHUNK; ++i)
    a[i] = (p0 + i < P) ? gmap[p0 + i] : 0;

  // issue all nng gathers (L2/L3-resident)
  #pragma unroll
  for (int i = 0; i < FCHUNK; ++i)
    gu[i] = *(const ushort4*)(g + (size_t)a[i] * F + lane * 4);

  // issue all ptg NT streams (12 independent 16B loads/lane)
  #pragma unroll
  for (int i = 0; i < FCHUNK; ++i) {
    const f32x4* gr = (const f32x4*)(ptg + (size_t)(p0 + i) * 3 * F);
    t0[i] = __builtin_nontemporal_load(gr + 0 * 64 + lane);
    t1[i] = __builtin_nontemporal_load(gr + 1 * 64 + lane);
    t2[i] = __builtin_nontemporal_load(gr + 2 * 64 + lane);
  }

  // reduce + scatter
  #pragma unroll
  for (int i = 0; i < FCHUNK; ++i) {
    if (p0 + i >= P) break;
    float g0 = bf2f(gu[i].x), g1 = bf2f(gu[i].y);
    float g2 = bf2f(gu[i].z), g3 = bf2f(gu[i].w);
    float s0 = t0[i][0] * g0 + t0[i][1] * g1 + t0[i][2] * g2 + t0[i][3] * g3;
    float s1 = t1[i][0] * g0 + t1[i][1] * g1 + t1[i][2] * g2 + t1[i][3] * g3;
    float s2 = t2[i][0] * g0 + t2[i][1] * g1 + t2[i][2] * g2 + t2[i][3] * g3;
    #pragma unroll
    for (int off = 32; off >= 1; off >>= 1) {
      s0 += __shfl_xor(s0, off, 64);
      s1 += __shfl_xor(s1, off, 64);
      s2 += __shfl_xor(s2, off, 64);
    }
    float r = (lane == 0) ? s0 : ((lane == 1) ? s1 : s2);
    if (lane < 3) atomicAdd(&forces[(size_t)a[i] * 3 + lane], -r);
  }
}

// ---------------- launch ----------------

extern "C" void kernel_launch(void* const* d_in, const int* in_sizes, int n_in,
                              void* d_out, int out_size, void* d_ws, size_t ws_size,
                              hipStream_t stream) {
  const float* X     = (const float*)d_in[0];
  const int*   z     = (const int*)d_in[1];
  const int*   smap  = (const int*)d_in[2];
  const float* ptg   = (const float*)d_in[3];
  const int*   gmap  = (const int*)d_in[4];
  const float* W1    = (const float*)d_in[5];
  const float* b1    = (const float*)d_in[6];
  const float* W2    = (const float*)d_in[7];
  const float* b2    = (const float*)d_in[8];
  const float* W3    = (const float*)d_in[9];
  const float* b3    = (const float*)d_in[10];
  const float* Wskip = (const float*)d_in[11];
  const float* bskip = (const float*)d_in[12];

  const int N = in_sizes[1];
  const int P = in_sizes[4];

  char* ws = (char*)d_ws;
  int* cnt  = (int*)ws;
  int* poff = (int*)(ws + 16);
  int* perm = (int*)(ws + 64);
  size_t perm_bytes = (size_t)(N + NSPEC * TM) * sizeof(int);
  size_t off = 64 + perm_bytes;
  off = (off + 255) & ~(size_t)255;
  unsigned short* Wf = (unsigned short*)(ws + off);
  const size_t WMAT = (size_t)NSPEC * 65536;
  off += 4 * WMAT * sizeof(unsigned short);
  off = (off + 255) & ~(size_t)255;
  unsigned short* nng = (unsigned short*)(ws + off);  // N * F bf16

  float* energies = (float*)d_out;
  float* forces   = energies + NSTRUCT;

  hipMemsetAsync(d_out, 0, (size_t)out_size * sizeof(float), stream);
  hipMemsetAsync(cnt, 0, 16, stream);

  prep_w<<<(4 * NSPEC * 8192 + 255) / 256, 256, 0, stream>>>(W1, W2, Wf);

  histogram_kernel<<<(N + 255) / 256, 256, 0, stream>>>(z, cnt, N);
  scan_kernel<<<1, 1, 0, stream>>>(cnt, poff, perm);
  scatter_kernel<<<(N + 255) / 256, 256, 0, stream>>>(z, poff, cnt, perm, N);

  int mlpBlocks = (N + NSPEC * TM + TM - 1) / TM;
  mlp_fused<<<mlpBlocks, 512, 0, stream>>>(X, smap, Wf, b1, b2, W3, b3,
                                           Wskip, bskip, perm, poff,
                                           energies, nng);

  int forceWaves = (P + FCHUNK - 1) / FCHUNK;
  int forceBlocks = (forceWaves + 3) / 4;
  force_kernel<<<forceBlocks, 256, 0, stream>>>(ptg, gmap, nng, forces, P);
}

// Round 12
// 394.337 us; speedup vs baseline: 1.2516x; 1.0057x over previous
//
#include <hip/hip_runtime.h>
#include <cstddef>

#define F 256
#define H 256
#define NSTRUCT 1000
#define NSPEC 4
#define TM 64      // tile rows / species padding granularity
#define TPAD 264   // LDS row stride in bf16 elems
#define FCHUNK 4   // pairs per wave in force kernel

typedef __attribute__((ext_vector_type(8))) short bf16x8;
typedef __attribute__((ext_vector_type(4))) float f32x4;

__device__ __forceinline__ unsigned short f2bf(float v) {
  unsigned int u = __float_as_uint(v);
  unsigned int r = (u + 0x7FFFu + ((u >> 16) & 1u)) >> 16;  // RNE
  return (unsigned short)r;
}

__device__ __forceinline__ float bf2f(unsigned short v) {
  return __uint_as_float(((unsigned int)v) << 16);
}

__device__ __forceinline__ float tanh_fast(float x) {
  x = fminf(fmaxf(x, -15.f), 15.f);
  float e = __expf(2.f * x);
  return __fdividef(e - 1.f, e + 1.f);
}

// DPP wave-64 sum: result valid on lane 63. row_shr 1/2/4/8 then bcast15/31.
__device__ __forceinline__ float dpp_sum64(float v) {
  float t;
  t = __int_as_float(__builtin_amdgcn_update_dpp(0, __float_as_int(v), 0x111, 0xf, 0xf, false)); v += t;
  t = __int_as_float(__builtin_amdgcn_update_dpp(0, __float_as_int(v), 0x112, 0xf, 0xf, false)); v += t;
  t = __int_as_float(__builtin_amdgcn_update_dpp(0, __float_as_int(v), 0x114, 0xf, 0xf, false)); v += t;
  t = __int_as_float(__builtin_amdgcn_update_dpp(0, __float_as_int(v), 0x118, 0xf, 0xf, false)); v += t;
  t = __int_as_float(__builtin_amdgcn_update_dpp(0, __float_as_int(v), 0x142, 0xa, 0xf, false)); v += t; // bcast15 -> rows 1,3
  t = __int_as_float(__builtin_amdgcn_update_dpp(0, __float_as_int(v), 0x143, 0xc, 0xf, false)); v += t; // bcast31 -> rows 2,3
  return v;
}

// ---------------- fused prep: weight packing + species histogram ----------------

// Pack W1, W2, W2^T, W1^T into bf16 MFMA-fragment order, kk-major:
// Out[m][s][kk][jt][lane][i] = W[k][j]  (k = kk*32+(lane>>4)*8+i, j = jt*16+(lane&15))
__global__ void prep_hist(const float* __restrict__ W1, const float* __restrict__ W2,
                          unsigned short* __restrict__ Out,
                          const int* __restrict__ z, int* __restrict__ cnt,
                          int N, int prepBlocks) {
  if ((int)blockIdx.x >= prepBlocks) {
    int i = (blockIdx.x - prepBlocks) * 256 + threadIdx.x;
    int lane = threadIdx.x & 63;
    int zi = (i < N) ? z[i] : -1;
    #pragma unroll
    for (int s = 0; s < NSPEC; ++s) {
      unsigned long long m = __ballot(zi == s);
      if (m != 0ull && lane == __ffsll((unsigned long long)m) - 1)
        atomicAdd(&cnt[s], __popcll(m));
    }
    return;
  }
  int t = blockIdx.x * 256 + threadIdx.x;
  int m = t >> 15;              // 0:W1 1:W2 2:W2^T 3:W1^T
  int u = t & 32767;
  int lane = u & 63, jt = (u >> 6) & 15, kk = (u >> 10) & 7, s = u >> 13;
  int trans = (m >= 2);
  const float* In = (m == 0 || m == 3) ? W1 : W2;
  int j = jt * 16 + (lane & 15);
  int k0 = kk * 32 + (lane >> 4) * 8;
  const float* base = In + (size_t)s * F * H;
  unsigned short o[8];
  #pragma unroll
  for (int i = 0; i < 8; ++i) {
    int k = k0 + i;
    float v = trans ? base[(size_t)j * 256 + k] : base[(size_t)k * 256 + j];
    o[i] = f2bf(v);
  }
  *(ushort4*)(Out + (size_t)t * 8) = make_ushort4(o[0], o[1], o[2], o[3]);
  *(ushort4*)(Out + (size_t)t * 8 + 4) = make_ushort4(o[4], o[5], o[6], o[7]);
}

// exclusive padded scan + fill pad slots of perm with -1
__global__ void scan_kernel(int* __restrict__ cnt, int* __restrict__ poff,
                            int* __restrict__ perm) {
  int acc = 0;
  for (int s = 0; s < NSPEC; ++s) {
    poff[s] = acc;
    int c = cnt[s];
    int padded = ((c + TM - 1) / TM) * TM;
    for (int i = acc + c; i < acc + padded; ++i) perm[i] = -1;
    acc += padded;
    cnt[s] = 0;
  }
  poff[NSPEC] = acc;
}

__global__ void scatter_kernel(const int* __restrict__ z, const int* __restrict__ poff,
                               int* __restrict__ cnt, int* __restrict__ perm, int N) {
  int i = blockIdx.x * blockDim.x + threadIdx.x;
  int lane = threadIdx.x & 63;
  int zi = (i < N) ? z[i] : -1;
  #pragma unroll
  for (int s = 0; s < NSPEC; ++s) {
    unsigned long long m = __ballot(zi == s);
    if (m == 0ull) continue;
    int leader = __ffsll((unsigned long long)m) - 1;
    int base = 0;
    if (lane == leader) base = atomicAdd(&cnt[s], __popcll(m));
    base = __shfl(base, leader, 64);
    if (zi == s) {
      int rank = __popcll(m & ((1ull << lane) - 1ull));
      perm[poff[s] + base + rank] = i;
    }
  }
}

// ---------------- GEMM core (wave w -> col-tiles {2w,2w+1}, all 4 row-frags) ----------------

__device__ __forceinline__ void gemm64(const unsigned short (*src)[TPAD],
                                       const unsigned short* __restrict__ wf,
                                       int w, int lane, f32x4 acc[4][2]) {
  const int l15 = lane & 15, lk = lane >> 4;
  #pragma unroll
  for (int rt = 0; rt < 4; ++rt)
    #pragma unroll
    for (int q = 0; q < 2; ++q) acc[rt][q] = (f32x4){0.f, 0.f, 0.f, 0.f};
  #pragma unroll
  for (int kk = 0; kk < 8; ++kk) {
    const int kcol = kk * 32 + lk * 8;
    bf16x8 a0 = *(const bf16x8*)&src[l15][kcol];
    bf16x8 a1 = *(const bf16x8*)&src[16 + l15][kcol];
    bf16x8 a2 = *(const bf16x8*)&src[32 + l15][kcol];
    bf16x8 a3 = *(const bf16x8*)&src[48 + l15][kcol];
    #pragma unroll
    for (int q = 0; q < 2; ++q) {
      const int jt = w * 2 + q;
      bf16x8 b = *(const bf16x8*)(wf + ((size_t)(kk * 16 + jt) * 64 + lane) * 8);
      acc[0][q] = __builtin_amdgcn_mfma_f32_16x16x32_bf16(a0, b, acc[0][q], 0, 0, 0);
      acc[1][q] = __builtin_amdgcn_mfma_f32_16x16x32_bf16(a1, b, acc[1][q], 0, 0, 0);
      acc[2][q] = __builtin_amdgcn_mfma_f32_16x16x32_bf16(a2, b, acc[2][q], 0, 0, 0);
      acc[3][q] = __builtin_amdgcn_mfma_f32_16x16x32_bf16(a3, b, acc[3][q], 0, 0, 0);
    }
  }
}

// ---------------- fused MFMA MLP fwd+bwd (round-3/8 structure) ----------------

__global__ __launch_bounds__(512, 4) void mlp_fused(
    const float* __restrict__ X, const int* __restrict__ smap,
    const unsigned short* __restrict__ Wf,
    const float* __restrict__ b1g, const float* __restrict__ b2g,
    const float* __restrict__ W3g, const float* __restrict__ b3g,
    const float* __restrict__ Wskipg, const float* __restrict__ bskipg,
    const int* __restrict__ perm, const int* __restrict__ poff,
    float* __restrict__ energies, unsigned short* __restrict__ nng)
{
  __shared__ __align__(16) unsigned short bufA[TM][TPAD];
  __shared__ __align__(16) unsigned short bufB[TM][TPAD];
  __shared__ float xskp[TM][8];
  __shared__ float e_lds[TM];
  __shared__ int atom_l[TM];

  const int tid = threadIdx.x;
  const int row0 = blockIdx.x * TM;
  if (row0 >= poff[NSPEC]) return;

  int s = 0;
  #pragma unroll
  for (int q = 1; q < NSPEC; ++q)
    if (row0 >= poff[q]) s = q;

  const size_t WMAT = (size_t)NSPEC * 65536;
  const unsigned short* w1f  = Wf + (size_t)s * 65536;
  const unsigned short* w2f  = Wf + WMAT + (size_t)s * 65536;
  const unsigned short* w2tf = Wf + 2 * WMAT + (size_t)s * 65536;
  const unsigned short* w1tf = Wf + 3 * WMAT + (size_t)s * 65536;
  const float* wsk = Wskipg + s * F;

  // ---- phase 0: stage X (fp32->bf16, nontemporal) + skip-dot partials ----
  {
    const int lr = tid >> 3, lc = tid & 7;
    if (tid < TM) { e_lds[tid] = 0.f; atom_l[tid] = perm[row0 + tid]; }
    const int atomR = perm[row0 + lr];
    float xsk = 0.f;
    if (atomR >= 0) {
      const f32x4* xrow = (const f32x4*)(X + (size_t)atomR * F);
      #pragma unroll
      for (int jj = 0; jj < 8; ++jj) {
        const int fi = lc + jj * 8;
        f32x4 v = __builtin_nontemporal_load(xrow + fi);
        float4 wv = ((const float4*)wsk)[fi];
        xsk += v[0] * wv.x + v[1] * wv.y + v[2] * wv.z + v[3] * wv.w;
        *(ushort4*)&bufA[lr][fi * 4] =
            make_ushort4(f2bf(v[0]), f2bf(v[1]), f2bf(v[2]), f2bf(v[3]));
      }
    } else {
      #pragma unroll
      for (int jj = 0; jj < 8; ++jj)
        *(ushort4*)&bufA[lr][(lc + jj * 8) * 4] = make_ushort4(0, 0, 0, 0);
    }
    xskp[lr][lc] = xsk;
  }
  __syncthreads();

  const int w = tid >> 6, lane = tid & 63;
  const int l15 = lane & 15, lk = lane >> 4;
  f32x4 acc[4][2];

  // ---- GEMM1: h1 = tanh(X @ W1 + b1) -> bufB ----
  gemm64(bufA, w1f, w, lane, acc);
  #pragma unroll
  for (int q = 0; q < 2; ++q) {
    const int col = (w * 2 + q) * 16 + l15;
    const float b1v = b1g[s * H + col];
    #pragma unroll
    for (int rt = 0; rt < 4; ++rt) {
      const int rowb = rt * 16 + lk * 4;
      #pragma unroll
      for (int r = 0; r < 4; ++r)
        bufB[rowb + r][col] = f2bf(tanh_fast(acc[rt][q][r] + b1v));
    }
  }
  __syncthreads();

  // ---- GEMM2: h2 = tanh(h1 @ W2 + b2); energy partials; d2 = (1-h2^2)*W3 -> bufA ----
  gemm64(bufB, w2f, w, lane, acc);
  {
    float ep[4][4];
    #pragma unroll
    for (int rt = 0; rt < 4; ++rt)
      #pragma unroll
      for (int r = 0; r < 4; ++r) ep[rt][r] = 0.f;
    #pragma unroll
    for (int q = 0; q < 2; ++q) {
      const int col = (w * 2 + q) * 16 + l15;
      const float b2v = b2g[s * H + col];
      const float w3v = W3g[s * H + col];
      #pragma unroll
      for (int rt = 0; rt < 4; ++rt) {
        const int rowb = rt * 16 + lk * 4;
        #pragma unroll
        for (int r = 0; r < 4; ++r) {
          float h = tanh_fast(acc[rt][q][r] + b2v);
          ep[rt][r] += h * w3v;
          bufA[rowb + r][col] = f2bf((1.f - h * h) * w3v);
        }
      }
    }
    #pragma unroll
    for (int rt = 0; rt < 4; ++rt)
      #pragma unroll
      for (int r = 0; r < 4; ++r) {
        #pragma unroll
        for (int m = 1; m <= 8; m <<= 1)
          ep[rt][r] += __shfl_xor(ep[rt][r], m, 64);
      }
    if (l15 == 0) {
      #pragma unroll
      for (int rt = 0; rt < 4; ++rt)
        #pragma unroll
        for (int r = 0; r < 4; ++r)
          atomicAdd(&e_lds[rt * 16 + lk * 4 + r], ep[rt][r]);
    }
  }
  __syncthreads();

  // ---- energies finalize ----
  if (tid < TM) {
    int atom = atom_l[tid];
    if (atom >= 0) {
      float xs = 0.f;
      #pragma unroll
      for (int q = 0; q < 8; ++q) xs += xskp[tid][q];
      atomicAdd(&energies[smap[atom]], e_lds[tid] + xs + b3g[s] + bskipg[s]);
    }
  }

  // ---- GEMM3: g1 = d2 @ W2^T; d1 = (1-h1^2)*g1 -> bufB (in-place h1 RMW) ----
  gemm64(bufA, w2tf, w, lane, acc);
  #pragma unroll
  for (int q = 0; q < 2; ++q) {
    const int col = (w * 2 + q) * 16 + l15;
    #pragma unroll
    for (int rt = 0; rt < 4; ++rt) {
      const int rowb = rt * 16 + lk * 4;
      #pragma unroll
      for (int r = 0; r < 4; ++r) {
        float h = bf2f(bufB[rowb + r][col]);
        bufB[rowb + r][col] = f2bf((1.f - h * h) * acc[rt][q][r]);
      }
    }
  }
  __syncthreads();

  // ---- GEMM4: dE/dx = d1 @ W1^T + Wskip -> nng (bf16) ----
  gemm64(bufB, w1tf, w, lane, acc);
  #pragma unroll
  for (int q = 0; q < 2; ++q) {
    const int col = (w * 2 + q) * 16 + l15;
    const float wv = wsk[col];
    #pragma unroll
    for (int rt = 0; rt < 4; ++rt) {
      #pragma unroll
      for (int r = 0; r < 4; ++r) {
        int atom2 = atom_l[rt * 16 + lk * 4 + r];
        if (atom2 >= 0)
          nng[(size_t)atom2 * F + col] = f2bf(acc[rt][q][r] + wv);
      }
    }
  }
}

// ---------------- forces: 1 wave per pair, 4 chunked, DPP reduce ----------------

__global__ __launch_bounds__(256) void force_kernel(
    const float* __restrict__ ptg, const int* __restrict__ gmap,
    const unsigned short* __restrict__ g, float* __restrict__ forces, int P)
{
  const int wave = (int)((blockIdx.x * 256 + threadIdx.x) >> 6);
  const int lane = threadIdx.x & 63;
  const int p0 = wave * FCHUNK;
  if (p0 >= P) return;

  int a[FCHUNK];
  ushort4 gu[FCHUNK];
  f32x4 t0[FCHUNK], t1[FCHUNK], t2[FCHUNK];

  #pragma unroll
  for (int i = 0; i < FCHUNK; ++i) {
    const int pi = (p0 + i < P) ? (p0 + i) : (P - 1);
    a[i] = gmap[pi];
  }

  #pragma unroll
  for (int i = 0; i < FCHUNK; ++i)
    gu[i] = *(const ushort4*)(g + (size_t)a[i] * F + lane * 4);

  #pragma unroll
  for (int i = 0; i < FCHUNK; ++i) {
    const int pi = (p0 + i < P) ? (p0 + i) : (P - 1);
    const f32x4* gr = (const f32x4*)(ptg + (size_t)pi * 3 * F);
    t0[i] = __builtin_nontemporal_load(gr + 0 * 64 + lane);
    t1[i] = __builtin_nontemporal_load(gr + 1 * 64 + lane);
    t2[i] = __builtin_nontemporal_load(gr + 2 * 64 + lane);
  }

  #pragma unroll
  for (int i = 0; i < FCHUNK; ++i) {
    if (p0 + i >= P) break;
    float g0 = bf2f(gu[i].x), g1 = bf2f(gu[i].y);
    float g2 = bf2f(gu[i].z), g3 = bf2f(gu[i].w);
    float s0 = t0[i][0] * g0 + t0[i][1] * g1 + t0[i][2] * g2 + t0[i][3] * g3;
    float s1 = t1[i][0] * g0 + t1[i][1] * g1 + t1[i][2] * g2 + t1[i][3] * g3;
    float s2 = t2[i][0] * g0 + t2[i][1] * g1 + t2[i][2] * g2 + t2[i][3] * g3;
    s0 = dpp_sum64(s0);
    s1 = dpp_sum64(s1);
    s2 = dpp_sum64(s2);
    if (lane == 63) {
      float* fa = forces + (size_t)a[i] * 3;
      atomicAdd(fa + 0, -s0);
      atomicAdd(fa + 1, -s1);
      atomicAdd(fa + 2, -s2);
    }
  }
}

// ---------------- launch ----------------

extern "C" void kernel_launch(void* const* d_in, const int* in_sizes, int n_in,
                              void* d_out, int out_size, void* d_ws, size_t ws_size,
                              hipStream_t stream) {
  const float* X     = (const float*)d_in[0];
  const int*   z     = (const int*)d_in[1];
  const int*   smap  = (const int*)d_in[2];
  const float* ptg   = (const float*)d_in[3];
  const int*   gmap  = (const int*)d_in[4];
  const float* W1    = (const float*)d_in[5];
  const float* b1    = (const float*)d_in[6];
  const float* W2    = (const float*)d_in[7];
  const float* b2    = (const float*)d_in[8];
  const float* W3    = (const float*)d_in[9];
  const float* b3    = (const float*)d_in[10];
  const float* Wskip = (const float*)d_in[11];
  const float* bskip = (const float*)d_in[12];

  const int N = in_sizes[1];
  const int P = in_sizes[4];

  char* ws = (char*)d_ws;
  int* cnt  = (int*)ws;
  int* poff = (int*)(ws + 16);
  int* perm = (int*)(ws + 64);
  size_t perm_bytes = (size_t)(N + NSPEC * TM) * sizeof(int);
  size_t off = 64 + perm_bytes;
  off = (off + 255) & ~(size_t)255;
  unsigned short* Wf = (unsigned short*)(ws + off);
  const size_t WMAT = (size_t)NSPEC * 65536;
  off += 4 * WMAT * sizeof(unsigned short);
  off = (off + 255) & ~(size_t)255;
  unsigned short* nng = (unsigned short*)(ws + off);  // N * F bf16

  float* energies = (float*)d_out;
  float* forces   = energies + NSTRUCT;

  hipMemsetAsync(d_out, 0, (size_t)out_size * sizeof(float), stream);
  hipMemsetAsync(cnt, 0, 16, stream);

  const int prepBlocks = (4 * NSPEC * 8192 + 255) / 256;
  const int histBlocks = (N + 255) / 256;
  prep_hist<<<prepBlocks + histBlocks, 256, 0, stream>>>(W1, W2, Wf, z, cnt, N, prepBlocks);
  scan_kernel<<<1, 1, 0, stream>>>(cnt, poff, perm);
  scatter_kernel<<<(N + 255) / 256, 256, 0, stream>>>(z, poff, cnt, perm, N);

  int mlpBlocks = (N + NSPEC * TM + TM - 1) / TM;
  mlp_fused<<<mlpBlocks, 512, 0, stream>>>(X, smap, Wf, b1, b2, W3, b3,
                                           Wskip, bskip, perm, poff,
                                           energies, nng);

  int forceWaves = (P + FCHUNK - 1) / FCHUNK;
  int forceBlocks = (forceWaves + 3) / 4;
  force_kernel<<<forceBlocks, 256, 0, stream>>>(ptg, gmap, nng, forces, P);
}

// Round 13
// 321.611 us; speedup vs baseline: 1.5346x; 1.2261x over previous
//
#include <hip/hip_runtime.h>
#include <cstddef>

#define F 256
#define H 256
#define NSTRUCT 1000
#define NSPEC 4
#define TM 64      // tile rows / species padding granularity
#define TPAD 264   // LDS row stride in bf16 elems
#define FCHUNK 4   // pairs per wave in force kernel

typedef __attribute__((ext_vector_type(8))) short bf16x8;
typedef __attribute__((ext_vector_type(4))) float f32x4;

__device__ __forceinline__ unsigned short f2bf(float v) {
  unsigned int u = __float_as_uint(v);
  unsigned int r = (u + 0x7FFFu + ((u >> 16) & 1u)) >> 16;  // RNE
  return (unsigned short)r;
}

__device__ __forceinline__ float bf2f(unsigned short v) {
  return __uint_as_float(((unsigned int)v) << 16);
}

__device__ __forceinline__ float tanh_fast(float x) {
  x = fminf(fmaxf(x, -15.f), 15.f);
  float e = __expf(2.f * x);
  return __fdividef(e - 1.f, e + 1.f);
}

// DPP wave-64 sum: result valid on lane 63. row_shr 1/2/4/8 then bcast15/31.
__device__ __forceinline__ float dpp_sum64(float v) {
  float t;
  t = __int_as_float(__builtin_amdgcn_update_dpp(0, __float_as_int(v), 0x111, 0xf, 0xf, false)); v += t;
  t = __int_as_float(__builtin_amdgcn_update_dpp(0, __float_as_int(v), 0x112, 0xf, 0xf, false)); v += t;
  t = __int_as_float(__builtin_amdgcn_update_dpp(0, __float_as_int(v), 0x114, 0xf, 0xf, false)); v += t;
  t = __int_as_float(__builtin_amdgcn_update_dpp(0, __float_as_int(v), 0x118, 0xf, 0xf, false)); v += t;
  t = __int_as_float(__builtin_amdgcn_update_dpp(0, __float_as_int(v), 0x142, 0xa, 0xf, false)); v += t; // bcast15 -> rows 1,3
  t = __int_as_float(__builtin_amdgcn_update_dpp(0, __float_as_int(v), 0x143, 0xc, 0xf, false)); v += t; // bcast31 -> rows 2,3
  return v;
}

// ---------------- fused prep: weight packing + d_out zeroing + species histogram ----------------

// Pack W1, W2, W2^T, W1^T into bf16 MFMA-fragment order, kk-major:
// Out[m][s][kk][jt][lane][i] = W[k][j]  (k = kk*32+(lane>>4)*8+i, j = jt*16+(lane&15))
// Blocks >= prepBlocks: per-block LDS histogram -> partial[hb][4] (no global pre-zero needed).
__global__ void prep_hist(const float* __restrict__ W1, const float* __restrict__ W2,
                          unsigned short* __restrict__ Out,
                          const int* __restrict__ z, int* __restrict__ partial,
                          float* __restrict__ outz, int out_elems,
                          int N, int prepBlocks) {
  if ((int)blockIdx.x >= prepBlocks) {
    __shared__ int lcnt[NSPEC];
    if (threadIdx.x < NSPEC) lcnt[threadIdx.x] = 0;
    __syncthreads();
    const int hb = blockIdx.x - prepBlocks;
    int i = hb * 256 + threadIdx.x;
    int lane = threadIdx.x & 63;
    int zi = (i < N) ? z[i] : -1;
    #pragma unroll
    for (int s = 0; s < NSPEC; ++s) {
      unsigned long long m = __ballot(zi == s);
      if (m != 0ull && lane == __ffsll((unsigned long long)m) - 1)
        atomicAdd(&lcnt[s], __popcll(m));
    }
    __syncthreads();
    if (threadIdx.x < NSPEC) partial[hb * NSPEC + threadIdx.x] = lcnt[threadIdx.x];
    return;
  }
  int t = blockIdx.x * 256 + threadIdx.x;
  // zero d_out (energies + forces) grid-stride over the prep region
  for (int i = t; i < out_elems; i += prepBlocks * 256) outz[i] = 0.f;

  int m = t >> 15;              // 0:W1 1:W2 2:W2^T 3:W1^T
  int u = t & 32767;
  int lane = u & 63, jt = (u >> 6) & 15, kk = (u >> 10) & 7, s = u >> 13;
  int trans = (m >= 2);
  const float* In = (m == 0 || m == 3) ? W1 : W2;
  int j = jt * 16 + (lane & 15);
  int k0 = kk * 32 + (lane >> 4) * 8;
  const float* base = In + (size_t)s * F * H;
  unsigned short o[8];
  #pragma unroll
  for (int i = 0; i < 8; ++i) {
    int k = k0 + i;
    float v = trans ? base[(size_t)j * 256 + k] : base[(size_t)k * 256 + j];
    o[i] = f2bf(v);
  }
  *(ushort4*)(Out + (size_t)t * 8) = make_ushort4(o[0], o[1], o[2], o[3]);
  *(ushort4*)(Out + (size_t)t * 8 + 4) = make_ushort4(o[4], o[5], o[6], o[7]);
}

// parallel partial-sum + serial padded exclusive scan; fills perm pad slots; zeroes cnt cursors
__global__ void scan_kernel(const int* __restrict__ partial, int nparts,
                            int* __restrict__ poff, int* __restrict__ cnt,
                            int* __restrict__ perm) {
  __shared__ int sum[NSPEC][64];
  const int t = threadIdx.x;           // 256 threads
  const int s = t & 3, g = t >> 2;     // 64 groups x 4 species
  int acc = 0;
  for (int b = g; b < nparts; b += 64) acc += partial[b * NSPEC + s];
  sum[s][g] = acc;
  __syncthreads();
  if (t == 0) {
    int acc2 = 0;
    for (int sp = 0; sp < NSPEC; ++sp) {
      int c = 0;
      for (int g2 = 0; g2 < 64; ++g2) c += sum[sp][g2];
      poff[sp] = acc2;
      int padded = ((c + TM - 1) / TM) * TM;
      for (int i = acc2 + c; i < acc2 + padded; ++i) perm[i] = -1;
      acc2 += padded;
      cnt[sp] = 0;
    }
    poff[NSPEC] = acc2;
  }
}

__global__ void scatter_kernel(const int* __restrict__ z, const int* __restrict__ poff,
                               int* __restrict__ cnt, int* __restrict__ perm, int N) {
  int i = blockIdx.x * blockDim.x + threadIdx.x;
  int lane = threadIdx.x & 63;
  int zi = (i < N) ? z[i] : -1;
  #pragma unroll
  for (int s = 0; s < NSPEC; ++s) {
    unsigned long long m = __ballot(zi == s);
    if (m == 0ull) continue;
    int leader = __ffsll((unsigned long long)m) - 1;
    int base = 0;
    if (lane == leader) base = atomicAdd(&cnt[s], __popcll(m));
    base = __shfl(base, leader, 64);
    if (zi == s) {
      int rank = __popcll(m & ((1ull << lane) - 1ull));
      perm[poff[s] + base + rank] = i;
    }
  }
}

// ---------------- GEMM core (wave w -> col-tiles {2w,2w+1}, all 4 row-frags) ----------------

__device__ __forceinline__ void gemm64(const unsigned short (*src)[TPAD],
                                       const unsigned short* __restrict__ wf,
                                       int w, int lane, f32x4 acc[4][2]) {
  const int l15 = lane & 15, lk = lane >> 4;
  #pragma unroll
  for (int rt = 0; rt < 4; ++rt)
    #pragma unroll
    for (int q = 0; q < 2; ++q) acc[rt][q] = (f32x4){0.f, 0.f, 0.f, 0.f};
  #pragma unroll
  for (int kk = 0; kk < 8; ++kk) {
    const int kcol = kk * 32 + lk * 8;
    bf16x8 a0 = *(const bf16x8*)&src[l15][kcol];
    bf16x8 a1 = *(const bf16x8*)&src[16 + l15][kcol];
    bf16x8 a2 = *(const bf16x8*)&src[32 + l15][kcol];
    bf16x8 a3 = *(const bf16x8*)&src[48 + l15][kcol];
    #pragma unroll
    for (int q = 0; q < 2; ++q) {
      const int jt = w * 2 + q;
      bf16x8 b = *(const bf16x8*)(wf + ((size_t)(kk * 16 + jt) * 64 + lane) * 8);
      acc[0][q] = __builtin_amdgcn_mfma_f32_16x16x32_bf16(a0, b, acc[0][q], 0, 0, 0);
      acc[1][q] = __builtin_amdgcn_mfma_f32_16x16x32_bf16(a1, b, acc[1][q], 0, 0, 0);
      acc[2][q] = __builtin_amdgcn_mfma_f32_16x16x32_bf16(a2, b, acc[2][q], 0, 0, 0);
      acc[3][q] = __builtin_amdgcn_mfma_f32_16x16x32_bf16(a3, b, acc[3][q], 0, 0, 0);
    }
  }
}

// ---------------- fused MFMA MLP fwd+bwd (round-3/8 structure) ----------------

__global__ __launch_bounds__(512, 4) void mlp_fused(
    const float* __restrict__ X, const int* __restrict__ smap,
    const unsigned short* __restrict__ Wf,
    const float* __restrict__ b1g, const float* __restrict__ b2g,
    const float* __restrict__ W3g, const float* __restrict__ b3g,
    const float* __restrict__ Wskipg, const float* __restrict__ bskipg,
    const int* __restrict__ perm, const int* __restrict__ poff,
    float* __restrict__ energies, unsigned short* __restrict__ nng)
{
  __shared__ __align__(16) unsigned short bufA[TM][TPAD];
  __shared__ __align__(16) unsigned short bufB[TM][TPAD];
  __shared__ float xskp[TM][8];
  __shared__ float e_lds[TM];
  __shared__ int atom_l[TM];

  const int tid = threadIdx.x;
  const int row0 = blockIdx.x * TM;
  if (row0 >= poff[NSPEC]) return;

  int s = 0;
  #pragma unroll
  for (int q = 1; q < NSPEC; ++q)
    if (row0 >= poff[q]) s = q;

  const size_t WMAT = (size_t)NSPEC * 65536;
  const unsigned short* w1f  = Wf + (size_t)s * 65536;
  const unsigned short* w2f  = Wf + WMAT + (size_t)s * 65536;
  const unsigned short* w2tf = Wf + 2 * WMAT + (size_t)s * 65536;
  const unsigned short* w1tf = Wf + 3 * WMAT + (size_t)s * 65536;
  const float* wsk = Wskipg + s * F;

  // ---- phase 0: stage X (fp32->bf16, nontemporal) + skip-dot partials ----
  {
    const int lr = tid >> 3, lc = tid & 7;
    if (tid < TM) { e_lds[tid] = 0.f; atom_l[tid] = perm[row0 + tid]; }
    const int atomR = perm[row0 + lr];
    float xsk = 0.f;
    if (atomR >= 0) {
      const f32x4* xrow = (const f32x4*)(X + (size_t)atomR * F);
      #pragma unroll
      for (int jj = 0; jj < 8; ++jj) {
        const int fi = lc + jj * 8;
        f32x4 v = __builtin_nontemporal_load(xrow + fi);
        float4 wv = ((const float4*)wsk)[fi];
        xsk += v[0] * wv.x + v[1] * wv.y + v[2] * wv.z + v[3] * wv.w;
        *(ushort4*)&bufA[lr][fi * 4] =
            make_ushort4(f2bf(v[0]), f2bf(v[1]), f2bf(v[2]), f2bf(v[3]));
      }
    } else {
      #pragma unroll
      for (int jj = 0; jj < 8; ++jj)
        *(ushort4*)&bufA[lr][(lc + jj * 8) * 4] = make_ushort4(0, 0, 0, 0);
    }
    xskp[lr][lc] = xsk;
  }
  __syncthreads();

  const int w = tid >> 6, lane = tid & 63;
  const int l15 = lane & 15, lk = lane >> 4;
  f32x4 acc[4][2];

  // ---- GEMM1: h1 = tanh(X @ W1 + b1) -> bufB ----
  gemm64(bufA, w1f, w, lane, acc);
  #pragma unroll
  for (int q = 0; q < 2; ++q) {
    const int col = (w * 2 + q) * 16 + l15;
    const float b1v = b1g[s * H + col];
    #pragma unroll
    for (int rt = 0; rt < 4; ++rt) {
      const int rowb = rt * 16 + lk * 4;
      #pragma unroll
      for (int r = 0; r < 4; ++r)
        bufB[rowb + r][col] = f2bf(tanh_fast(acc[rt][q][r] + b1v));
    }
  }
  __syncthreads();

  // ---- GEMM2: h2 = tanh(h1 @ W2 + b2); energy partials; d2 = (1-h2^2)*W3 -> bufA ----
  gemm64(bufB, w2f, w, lane, acc);
  {
    float ep[4][4];
    #pragma unroll
    for (int rt = 0; rt < 4; ++rt)
      #pragma unroll
      for (int r = 0; r < 4; ++r) ep[rt][r] = 0.f;
    #pragma unroll
    for (int q = 0; q < 2; ++q) {
      const int col = (w * 2 + q) * 16 + l15;
      const float b2v = b2g[s * H + col];
      const float w3v = W3g[s * H + col];
      #pragma unroll
      for (int rt = 0; rt < 4; ++rt) {
        const int rowb = rt * 16 + lk * 4;
        #pragma unroll
        for (int r = 0; r < 4; ++r) {
          float h = tanh_fast(acc[rt][q][r] + b2v);
          ep[rt][r] += h * w3v;
          bufA[rowb + r][col] = f2bf((1.f - h * h) * w3v);
        }
      }
    }
    #pragma unroll
    for (int rt = 0; rt < 4; ++rt)
      #pragma unroll
      for (int r = 0; r < 4; ++r) {
        #pragma unroll
        for (int m = 1; m <= 8; m <<= 1)
          ep[rt][r] += __shfl_xor(ep[rt][r], m, 64);
      }
    if (l15 == 0) {
      #pragma unroll
      for (int rt = 0; rt < 4; ++rt)
        #pragma unroll
        for (int r = 0; r < 4; ++r)
          atomicAdd(&e_lds[rt * 16 + lk * 4 + r], ep[rt][r]);
    }
  }
  __syncthreads();

  // ---- energies finalize ----
  if (tid < TM) {
    int atom = atom_l[tid];
    if (atom >= 0) {
      float xs = 0.f;
      #pragma unroll
      for (int q = 0; q < 8; ++q) xs += xskp[tid][q];
      atomicAdd(&energies[smap[atom]], e_lds[tid] + xs + b3g[s] + bskipg[s]);
    }
  }

  // ---- GEMM3: g1 = d2 @ W2^T; d1 = (1-h1^2)*g1 -> bufB (in-place h1 RMW) ----
  gemm64(bufA, w2tf, w, lane, acc);
  #pragma unroll
  for (int q = 0; q < 2; ++q) {
    const int col = (w * 2 + q) * 16 + l15;
    #pragma unroll
    for (int rt = 0; rt < 4; ++rt) {
      const int rowb = rt * 16 + lk * 4;
      #pragma unroll
      for (int r = 0; r < 4; ++r) {
        float h = bf2f(bufB[rowb + r][col]);
        bufB[rowb + r][col] = f2bf((1.f - h * h) * acc[rt][q][r]);
      }
    }
  }
  __syncthreads();

  // ---- GEMM4: dE/dx = d1 @ W1^T + Wskip -> nng (bf16) ----
  gemm64(bufB, w1tf, w, lane, acc);
  #pragma unroll
  for (int q = 0; q < 2; ++q) {
    const int col = (w * 2 + q) * 16 + l15;
    const float wv = wsk[col];
    #pragma unroll
    for (int rt = 0; rt < 4; ++rt) {
      #pragma unroll
      for (int r = 0; r < 4; ++r) {
        int atom2 = atom_l[rt * 16 + lk * 4 + r];
        if (atom2 >= 0)
          nng[(size_t)atom2 * F + col] = f2bf(acc[rt][q][r] + wv);
      }
    }
  }
}

// ---------------- forces: 1 wave per pair, 4 chunked, DPP reduce ----------------

__global__ __launch_bounds__(256) void force_kernel(
    const float* __restrict__ ptg, const int* __restrict__ gmap,
    const unsigned short* __restrict__ g, float* __restrict__ forces, int P)
{
  const int wave = (int)((blockIdx.x * 256 + threadIdx.x) >> 6);
  const int lane = threadIdx.x & 63;
  const int p0 = wave * FCHUNK;
  if (p0 >= P) return;

  int a[FCHUNK];
  ushort4 gu[FCHUNK];
  f32x4 t0[FCHUNK], t1[FCHUNK], t2[FCHUNK];

  #pragma unroll
  for (int i = 0; i < FCHUNK; ++i) {
    const int pi = (p0 + i < P) ? (p0 + i) : (P - 1);
    a[i] = gmap[pi];
  }

  #pragma unroll
  for (int i = 0; i < FCHUNK; ++i)
    gu[i] = *(const ushort4*)(g + (size_t)a[i] * F + lane * 4);

  #pragma unroll
  for (int i = 0; i < FCHUNK; ++i) {
    const int pi = (p0 + i < P) ? (p0 + i) : (P - 1);
    const f32x4* gr = (const f32x4*)(ptg + (size_t)pi * 3 * F);
    t0[i] = __builtin_nontemporal_load(gr + 0 * 64 + lane);
    t1[i] = __builtin_nontemporal_load(gr + 1 * 64 + lane);
    t2[i] = __builtin_nontemporal_load(gr + 2 * 64 + lane);
  }

  #pragma unroll
  for (int i = 0; i < FCHUNK; ++i) {
    if (p0 + i >= P) break;
    float g0 = bf2f(gu[i].x), g1 = bf2f(gu[i].y);
    float g2 = bf2f(gu[i].z), g3 = bf2f(gu[i].w);
    float s0 = t0[i][0] * g0 + t0[i][1] * g1 + t0[i][2] * g2 + t0[i][3] * g3;
    float s1 = t1[i][0] * g0 + t1[i][1] * g1 + t1[i][2] * g2 + t1[i][3] * g3;
    float s2 = t2[i][0] * g0 + t2[i][1] * g1 + t2[i][2] * g2 + t2[i][3] * g3;
    s0 = dpp_sum64(s0);
    s1 = dpp_sum64(s1);
    s2 = dpp_sum64(s2);
    if (lane == 63) {
      float* fa = forces + (size_t)a[i] * 3;
      atomicAdd(fa + 0, -s0);
      atomicAdd(fa + 1, -s1);
      atomicAdd(fa + 2, -s2);
    }
  }
}

// ---------------- launch ----------------

extern "C" void kernel_launch(void* const* d_in, const int* in_sizes, int n_in,
                              void* d_out, int out_size, void* d_ws, size_t ws_size,
                              hipStream_t stream) {
  const float* X     = (const float*)d_in[0];
  const int*   z     = (const int*)d_in[1];
  const int*   smap  = (const int*)d_in[2];
  const float* ptg   = (const float*)d_in[3];
  const int*   gmap  = (const int*)d_in[4];
  const float* W1    = (const float*)d_in[5];
  const float* b1    = (const float*)d_in[6];
  const float* W2    = (const float*)d_in[7];
  const float* b2    = (const float*)d_in[8];
  const float* W3    = (const float*)d_in[9];
  const float* b3    = (const float*)d_in[10];
  const float* Wskip = (const float*)d_in[11];
  const float* bskip = (const float*)d_in[12];

  const int N = in_sizes[1];
  const int P = in_sizes[4];

  const int prepBlocks = (4 * NSPEC * 8192 + 255) / 256;  // 512
  const int histBlocks = (N + 255) / 256;

  char* ws = (char*)d_ws;
  int* cnt  = (int*)ws;
  int* poff = (int*)(ws + 16);
  int* perm = (int*)(ws + 64);
  size_t perm_bytes = (size_t)(N + NSPEC * TM) * sizeof(int);
  size_t off = 64 + perm_bytes;
  off = (off + 255) & ~(size_t)255;
  int* partial = (int*)(ws + off);
  off += (size_t)histBlocks * NSPEC * sizeof(int);
  off = (off + 255) & ~(size_t)255;
  unsigned short* Wf = (unsigned short*)(ws + off);
  const size_t WMAT = (size_t)NSPEC * 65536;
  off += 4 * WMAT * sizeof(unsigned short);
  off = (off + 255) & ~(size_t)255;
  unsigned short* nng = (unsigned short*)(ws + off);  // N * F bf16

  float* energies = (float*)d_out;
  float* forces   = energies + NSTRUCT;

  prep_hist<<<prepBlocks + histBlocks, 256, 0, stream>>>(
      W1, W2, Wf, z, partial, (float*)d_out, out_size, N, prepBlocks);
  scan_kernel<<<1, 256, 0, stream>>>(partial, histBlocks, poff, cnt, perm);
  scatter_kernel<<<histBlocks, 256, 0, stream>>>(z, poff, cnt, perm, N);

  int mlpBlocks = (N + NSPEC * TM + TM - 1) / TM;
  mlp_fused<<<mlpBlocks, 512, 0, stream>>>(X, smap, Wf, b1, b2, W3, b3,
                                           Wskip, bskip, perm, poff,
                                           energies, nng);

  int forceWaves = (P + FCHUNK - 1) / FCHUNK;
  int forceBlocks = (forceWaves + 3) / 4;
  force_kernel<<<forceBlocks, 256, 0, stream>>>(ptg, gmap, nng, forces, P);
}